// Round 8
// baseline (72.598 us; speedup 1.0000x reference)
//
#include <hip/hip_runtime.h>

// SourcePE: out[n,b,e] = dropout( emb[n,b,e] + sin(box[b,n,e&3] * den[e>>2]) )
// dropout mask = JAX threefry2x32, key(42)=(0,42), partitionable path:
//   bits(i) = out0 ^ out1 of threefry((0,42), (0, i))
//   keep <=> bits < 7549747*512 = 3865470464   (bit-exact, verified R1-R7)
//
// R8 = R7 (best: 69.4us; depth-4 pipeline, pointer math via const-indexed
// unroll) with ONE change: grid 4096 -> 8192 blocks. Occupancy scales with
// block granularity (2048blk=49%, 4096=63%, 8192=75% in R3) because
// 2048x4waves == exactly 1.0x wave capacity; finer blocks back-fill CU
// dispatch imbalance. Testing whether the fill converts to issue slots.

namespace {

typedef float f32x4 __attribute__((ext_vector_type(4)));

constexpr int      NBOX     = 1024;
constexpr unsigned TOTAL_G  = 1024u * 64u * 128u;  // 8388608 float4-groups
constexpr unsigned NBLK     = 8192;
constexpr unsigned NTHR     = 256;
constexpr unsigned STRIDE_G = NBLK * NTHR;         // 2097152 groups
constexpr int      ITERS    = TOTAL_G / STRIDE_G;  // 4
constexpr int      PFD      = 3;                   // prefetch distance (iters)
// per-thread: j = g&127 invariant, b invariant, n += 256 per iter.

__device__ __forceinline__ unsigned rotl(unsigned x, int r) {
  return __builtin_amdgcn_alignbit(x, x, 32 - r);  // 1-op rotate
}

// threefry2x32, key=(0,42): ks0=0, ks1=42, ks2=0x1BD11BDA^42=0x1BD11BF0
__device__ __forceinline__ unsigned threefry_xor(unsigned ctr) {
  unsigned x0 = 0u;          // ctr_hi + ks0
  unsigned x1 = ctr + 42u;   // ctr_lo + ks1
#define R4(a,b,c,d)                       \
  x0 += x1; x1 = rotl(x1,(a)) ^ x0;       \
  x0 += x1; x1 = rotl(x1,(b)) ^ x0;       \
  x0 += x1; x1 = rotl(x1,(c)) ^ x0;       \
  x0 += x1; x1 = rotl(x1,(d)) ^ x0;
  R4(13,15,26,6)
  x0 += 42u;          x1 += 0x1BD11BF1u;  // ks1, ks2+1
  R4(17,29,16,24)
  x0 += 0x1BD11BF0u;  x1 += 2u;           // ks2, ks0+2
  R4(13,15,26,6)
  /* ks0 = 0 */       x1 += 45u;          // ks1+3
  R4(17,29,16,24)
  x0 += 42u;          x1 += 0x1BD11BF4u;  // ks1, ks2+4
  R4(13,15,26,6)
  x0 += 0x1BD11BF0u;  x1 += 5u;           // ks2, ks0+5
#undef R4
  return x0 ^ x1;
}

__device__ __forceinline__ f32x4 body(const f32x4 e, const int4 bx,
                                      const float den, const unsigned i0) {
  const float SC = 1.11111111111111111f;  // 1/0.9
  const float s0 = __sinf((float)bx.x * den);
  const float s1 = __sinf((float)bx.y * den);
  const float s2 = __sinf((float)bx.z * den);
  const float s3 = __sinf((float)bx.w * den);

  const unsigned m0 = threefry_xor(i0);
  const unsigned m1 = threefry_xor(i0 + 1u);
  const unsigned m2 = threefry_xor(i0 + 2u);
  const unsigned m3 = threefry_xor(i0 + 3u);

  f32x4 r;
  r.x = (m0 < 3865470464u) ? (e.x + s0) * SC : 0.0f;
  r.y = (m1 < 3865470464u) ? (e.y + s1) * SC : 0.0f;
  r.z = (m2 < 3865470464u) ? (e.z + s2) * SC : 0.0f;
  r.w = (m3 < 3865470464u) ? (e.w + s3) * SC : 0.0f;
  return r;
}

__global__ __launch_bounds__(256) void pe_add_dropout(
    const f32x4* __restrict__ emb,
    const int4*  __restrict__ boxes,
    f32x4*       __restrict__ out) {
  const float K2 = 0.0064881408103268795f;  // log2(10000)/2048

  const unsigned g0   = blockIdx.x * NTHR + threadIdx.x;  // < 2097152
  const unsigned j    = g0 & 127u;
  const unsigned row0 = g0 >> 7;            // n*64 + b, < 16384
  const unsigned b    = row0 & 63u;
  const unsigned n0   = row0 >> 6;          // < 256

  const float den = exp2f(-(float)j * K2); // hoisted: j invariant

  const f32x4* ep = emb + g0;
  const int4*  bp = boxes + (b * NBOX + n0);
  f32x4*       op = out + g0;
  const unsigned i0 = g0 << 2;             // flat element index

  // 4-slot rotating register buffer; prologue loads iters 0..PFD-1
  f32x4 ebuf[4];
  int4  xbuf[4];
#pragma unroll
  for (int k = 0; k < PFD; ++k) {
    ebuf[k] = ep[(unsigned)k * STRIDE_G];
    xbuf[k] = bp[k * 256];
  }

#pragma unroll
  for (int it = 0; it < ITERS; ++it) {
    // issue prefetch for iteration it+PFD (constant condition under unroll)
    if (it + PFD < ITERS) {
      ebuf[(it + PFD) & 3] = ep[(unsigned)(it + PFD) * STRIDE_G];
      xbuf[(it + PFD) & 3] = bp[(it + PFD) * 256];
    }
    op[(unsigned)it * STRIDE_G] =
        body(ebuf[it & 3], xbuf[it & 3], den, i0 + (unsigned)it * (STRIDE_G * 4u));
  }
}

}  // namespace

extern "C" void kernel_launch(void* const* d_in, const int* in_sizes, int n_in,
                              void* d_out, int out_size, void* d_ws, size_t ws_size,
                              hipStream_t stream) {
  const f32x4* emb   = (const f32x4*)d_in[0];  // (1024, 64, 512) f32
  const int4*  boxes = (const int4*)d_in[1];   // (64, 1024, 4) i32
  f32x4*       outp  = (f32x4*)d_out;          // (1024, 64, 512) f32
  hipLaunchKernelGGL(pe_add_dropout, dim3(NBLK), dim3(NTHR), 0, stream,
                     emb, boxes, outp);
}

// Round 9
// 68.865 us; speedup vs baseline: 1.0542x; 1.0542x over previous
//
#include <hip/hip_runtime.h>

// SourcePE: out[n,b,e] = dropout( emb[n,b,e] + sin(box[b,n,e&3] * den[e>>2]) )
// dropout mask = JAX threefry2x32, key(42)=(0,42), partitionable path:
//   bits(i) = out0 ^ out1 of threefry((0,42), (0, i))
//   keep <=> bits < 7549747*512 = 3865470464   (bit-exact, verified R1-R8)
//
// R9 = R7 (best: 69.4us; 4096 blk, depth-4 rotating pipeline) with ONE
// change: nontemporal stores for `out`. Mechanism: 131MB of writes currently
// flow through L3 and evict emb (FETCH=66MB of a 128MB input => L3 serves
// half of emb across replays). NT stores bypass L3 -> emb becomes fully
// L3-resident -> FETCH collapses, read stalls shrink. Isolated test of the
// lever R3 bundled with two known-bad changes.

namespace {

typedef float f32x4 __attribute__((ext_vector_type(4)));

constexpr int      NBOX     = 1024;
constexpr unsigned TOTAL_G  = 1024u * 64u * 128u;  // 8388608 float4-groups
constexpr unsigned NBLK     = 4096;
constexpr unsigned NTHR     = 256;
constexpr unsigned STRIDE_G = NBLK * NTHR;         // 1048576 groups
constexpr int      ITERS    = TOTAL_G / STRIDE_G;  // 8
constexpr int      PFD      = 3;                   // prefetch distance (iters)
// per-thread: j = g&127 invariant, b invariant, n += 128 per iter.

__device__ __forceinline__ unsigned rotl(unsigned x, int r) {
  return __builtin_amdgcn_alignbit(x, x, 32 - r);  // 1-op rotate
}

// threefry2x32, key=(0,42): ks0=0, ks1=42, ks2=0x1BD11BDA^42=0x1BD11BF0
__device__ __forceinline__ unsigned threefry_xor(unsigned ctr) {
  unsigned x0 = 0u;          // ctr_hi + ks0
  unsigned x1 = ctr + 42u;   // ctr_lo + ks1
#define R4(a,b,c,d)                       \
  x0 += x1; x1 = rotl(x1,(a)) ^ x0;       \
  x0 += x1; x1 = rotl(x1,(b)) ^ x0;       \
  x0 += x1; x1 = rotl(x1,(c)) ^ x0;       \
  x0 += x1; x1 = rotl(x1,(d)) ^ x0;
  R4(13,15,26,6)
  x0 += 42u;          x1 += 0x1BD11BF1u;  // ks1, ks2+1
  R4(17,29,16,24)
  x0 += 0x1BD11BF0u;  x1 += 2u;           // ks2, ks0+2
  R4(13,15,26,6)
  /* ks0 = 0 */       x1 += 45u;          // ks1+3
  R4(17,29,16,24)
  x0 += 42u;          x1 += 0x1BD11BF4u;  // ks1, ks2+4
  R4(13,15,26,6)
  x0 += 0x1BD11BF0u;  x1 += 5u;           // ks2, ks0+5
#undef R4
  return x0 ^ x1;
}

__device__ __forceinline__ f32x4 body(const f32x4 e, const int4 bx,
                                      const float den, const unsigned i0) {
  const float SC = 1.11111111111111111f;  // 1/0.9
  const float s0 = __sinf((float)bx.x * den);
  const float s1 = __sinf((float)bx.y * den);
  const float s2 = __sinf((float)bx.z * den);
  const float s3 = __sinf((float)bx.w * den);

  const unsigned m0 = threefry_xor(i0);
  const unsigned m1 = threefry_xor(i0 + 1u);
  const unsigned m2 = threefry_xor(i0 + 2u);
  const unsigned m3 = threefry_xor(i0 + 3u);

  f32x4 r;
  r.x = (m0 < 3865470464u) ? (e.x + s0) * SC : 0.0f;
  r.y = (m1 < 3865470464u) ? (e.y + s1) * SC : 0.0f;
  r.z = (m2 < 3865470464u) ? (e.z + s2) * SC : 0.0f;
  r.w = (m3 < 3865470464u) ? (e.w + s3) * SC : 0.0f;
  return r;
}

__global__ __launch_bounds__(256) void pe_add_dropout(
    const f32x4* __restrict__ emb,
    const int4*  __restrict__ boxes,
    f32x4*       __restrict__ out) {
  const float K2 = 0.0064881408103268795f;  // log2(10000)/2048

  const unsigned g0   = blockIdx.x * NTHR + threadIdx.x;  // < 1048576
  const unsigned j    = g0 & 127u;
  const unsigned row0 = g0 >> 7;            // n*64 + b, < 8192
  const unsigned b    = row0 & 63u;
  const unsigned n0   = row0 >> 6;          // < 128

  const float den = exp2f(-(float)j * K2); // hoisted: j invariant

  const f32x4* ep = emb + g0;
  const int4*  bp = boxes + (b * NBOX + n0);
  f32x4*       op = out + g0;
  const unsigned i0 = g0 << 2;             // flat element index

  // 4-slot rotating register buffer; prologue loads iters 0..PFD-1
  f32x4 ebuf[4];
  int4  xbuf[4];
#pragma unroll
  for (int k = 0; k < PFD; ++k) {
    ebuf[k] = ep[(unsigned)k * STRIDE_G];
    xbuf[k] = bp[k * 128];
  }

#pragma unroll
  for (int it = 0; it < ITERS; ++it) {
    // issue prefetch for iteration it+PFD (constant condition under unroll)
    if (it + PFD < ITERS) {
      ebuf[(it + PFD) & 3] = ep[(unsigned)(it + PFD) * STRIDE_G];
      xbuf[(it + PFD) & 3] = bp[(it + PFD) * 128];
    }
    const f32x4 r =
        body(ebuf[it & 3], xbuf[it & 3], den, i0 + (unsigned)it * (STRIDE_G * 4u));
    __builtin_nontemporal_store(r, &op[(unsigned)it * STRIDE_G]);
  }
}

}  // namespace

extern "C" void kernel_launch(void* const* d_in, const int* in_sizes, int n_in,
                              void* d_out, int out_size, void* d_ws, size_t ws_size,
                              hipStream_t stream) {
  const f32x4* emb   = (const f32x4*)d_in[0];  // (1024, 64, 512) f32
  const int4*  boxes = (const int4*)d_in[1];   // (64, 1024, 4) i32
  f32x4*       outp  = (f32x4*)d_out;          // (1024, 64, 512) f32
  hipLaunchKernelGGL(pe_add_dropout, dim3(NBLK), dim3(NTHR), 0, stream,
                     emb, boxes, outp);
}

// Round 10
// 67.617 us; speedup vs baseline: 1.0737x; 1.0185x over previous
//
#include <hip/hip_runtime.h>

// SourcePE: out[n,b,e] = dropout( emb[n,b,e] + sin(box[b,n,e&3] * den[e>>2]) )
// dropout mask = JAX threefry2x32, key(42)=(0,42), partitionable path:
//   bits(i) = out0 ^ out1 of threefry((0,42), (0, i))
//   keep <=> bits < 7549747*512 = 3865470464   (bit-exact, verified R1-R9)
//
// R10 = R9 (best: 68.9us; 4096 blk, depth-4 rotating pipeline, nt store)
// + the two R5-verified micro-shaves, now isolated from R5's neutral
// 2-stream restructure: (a) fused-injection threefry (-8 ops/group),
// (b) 3-op sin via den_rev (1/2pi prefolded) + raw v_sin (-4 ops/group),
// + (c) s_setprio(1) around the pure-VALU body (T5: barrier-free staggered
// waves = the regime where setprio helps, unlike lockstep GEMM).

namespace {

typedef float f32x4 __attribute__((ext_vector_type(4)));

constexpr int      NBOX     = 1024;
constexpr unsigned TOTAL_G  = 1024u * 64u * 128u;  // 8388608 float4-groups
constexpr unsigned NBLK     = 4096;
constexpr unsigned NTHR     = 256;
constexpr unsigned STRIDE_G = NBLK * NTHR;         // 1048576 groups
constexpr int      ITERS    = TOTAL_G / STRIDE_G;  // 8
constexpr int      PFD      = 3;                   // prefetch distance (iters)
// per-thread: j = g&127 invariant, b invariant, n += 128 per iter.

__device__ __forceinline__ unsigned rotl(unsigned x, int r) {
  return __builtin_amdgcn_alignbit(x, x, 32 - r);  // 1-op rotate
}

// threefry2x32, key=(0,42): ks0=0, ks1=42, ks2=0x1BD11BDA^42=0x1BD11BF0
// Injection fusion: {x0+=ksA; x1+=ksB; x0+=x1} == {x1+=ksB; x0=x0+x1+ksA}.
// Bit-exact verified in R5 (absmax 0.03125 = sin error only).
__device__ __forceinline__ unsigned threefry_xor(unsigned ctr) {
  unsigned x1 = ctr + 42u;                 // ctr_lo + ks1
  unsigned x0 = x1;                        // round 1: x0 = 0 + x1
  x1 = rotl(x1,13) ^ x0;
  x0 += x1; x1 = rotl(x1,15) ^ x0;
  x0 += x1; x1 = rotl(x1,26) ^ x0;
  x0 += x1; x1 = rotl(x1, 6) ^ x0;
  x1 += 0x1BD11BF1u;                       // inj1: ks2+1
  x0 = x0 + x1 + 42u;                      // inj1: ks1, fused w/ round-5 add
  x1 = rotl(x1,17) ^ x0;
  x0 += x1; x1 = rotl(x1,29) ^ x0;
  x0 += x1; x1 = rotl(x1,16) ^ x0;
  x0 += x1; x1 = rotl(x1,24) ^ x0;
  x1 += 2u;                                // inj2: ks0+2
  x0 = x0 + x1 + 0x1BD11BF0u;              // inj2: ks2, fused
  x1 = rotl(x1,13) ^ x0;
  x0 += x1; x1 = rotl(x1,15) ^ x0;
  x0 += x1; x1 = rotl(x1,26) ^ x0;
  x0 += x1; x1 = rotl(x1, 6) ^ x0;
  x1 += 45u;                               // inj3: ks1+3 (ks0=0 side free)
  x0 += x1;
  x1 = rotl(x1,17) ^ x0;
  x0 += x1; x1 = rotl(x1,29) ^ x0;
  x0 += x1; x1 = rotl(x1,16) ^ x0;
  x0 += x1; x1 = rotl(x1,24) ^ x0;
  x1 += 0x1BD11BF4u;                       // inj4: ks2+4
  x0 = x0 + x1 + 42u;                      // inj4: ks1, fused
  x1 = rotl(x1,13) ^ x0;
  x0 += x1; x1 = rotl(x1,15) ^ x0;
  x0 += x1; x1 = rotl(x1,26) ^ x0;
  x0 += x1; x1 = rotl(x1, 6) ^ x0;
  return (x0 + 0x1BD11BF0u) ^ (x1 + 5u);   // inj5: ks2 / ks0+5, then combine
}

__device__ __forceinline__ f32x4 body(const f32x4 e, const int4 bx,
                                      const float den_rev, const unsigned i0) {
  const float SC = 1.11111111111111111f;  // 1/0.9
  // den_rev has 1/(2pi) folded in: v_sin takes revolutions (R5-verified).
  const float s0 = __builtin_amdgcn_sinf((float)bx.x * den_rev);
  const float s1 = __builtin_amdgcn_sinf((float)bx.y * den_rev);
  const float s2 = __builtin_amdgcn_sinf((float)bx.z * den_rev);
  const float s3 = __builtin_amdgcn_sinf((float)bx.w * den_rev);

  const unsigned m0 = threefry_xor(i0);
  const unsigned m1 = threefry_xor(i0 + 1u);
  const unsigned m2 = threefry_xor(i0 + 2u);
  const unsigned m3 = threefry_xor(i0 + 3u);

  f32x4 r;
  r.x = (m0 < 3865470464u) ? (e.x + s0) * SC : 0.0f;
  r.y = (m1 < 3865470464u) ? (e.y + s1) * SC : 0.0f;
  r.z = (m2 < 3865470464u) ? (e.z + s2) * SC : 0.0f;
  r.w = (m3 < 3865470464u) ? (e.w + s3) * SC : 0.0f;
  return r;
}

__global__ __launch_bounds__(256) void pe_add_dropout(
    const f32x4* __restrict__ emb,
    const int4*  __restrict__ boxes,
    f32x4*       __restrict__ out) {
  const float K2     = 0.0064881408103268795f;  // log2(10000)/2048
  const float INV2PI = 0.15915494309189535f;

  const unsigned g0   = blockIdx.x * NTHR + threadIdx.x;  // < 1048576
  const unsigned j    = g0 & 127u;
  const unsigned row0 = g0 >> 7;            // n*64 + b, < 8192
  const unsigned b    = row0 & 63u;
  const unsigned n0   = row0 >> 6;          // < 128

  const float den_rev = exp2f(-(float)j * K2) * INV2PI;  // hoisted

  const f32x4* ep = emb + g0;
  const int4*  bp = boxes + (b * NBOX + n0);
  f32x4*       op = out + g0;
  const unsigned i0 = g0 << 2;             // flat element index

  // 4-slot rotating register buffer; prologue loads iters 0..PFD-1
  f32x4 ebuf[4];
  int4  xbuf[4];
#pragma unroll
  for (int k = 0; k < PFD; ++k) {
    ebuf[k] = ep[(unsigned)k * STRIDE_G];
    xbuf[k] = bp[k * 128];
  }

#pragma unroll
  for (int it = 0; it < ITERS; ++it) {
    // issue prefetch for iteration it+PFD (constant condition under unroll)
    if (it + PFD < ITERS) {
      ebuf[(it + PFD) & 3] = ep[(unsigned)(it + PFD) * STRIDE_G];
      xbuf[(it + PFD) & 3] = bp[(it + PFD) * 128];
    }
    // pure-VALU region: raise wave priority so compute-phase waves win
    // issue arbitration over waves entering their load-wait window (T5).
    __builtin_amdgcn_s_setprio(1);
    const f32x4 r =
        body(ebuf[it & 3], xbuf[it & 3], den_rev, i0 + (unsigned)it * (STRIDE_G * 4u));
    __builtin_amdgcn_s_setprio(0);
    __builtin_nontemporal_store(r, &op[(unsigned)it * STRIDE_G]);
  }
}

}  // namespace

extern "C" void kernel_launch(void* const* d_in, const int* in_sizes, int n_in,
                              void* d_out, int out_size, void* d_ws, size_t ws_size,
                              hipStream_t stream) {
  const f32x4* emb   = (const f32x4*)d_in[0];  // (1024, 64, 512) f32
  const int4*  boxes = (const int4*)d_in[1];   // (64, 1024, 4) i32
  f32x4*       outp  = (f32x4*)d_out;          // (1024, 64, 512) f32
  hipLaunchKernelGGL(pe_add_dropout, dim3(NBLK), dim3(NTHR), 0, stream,
                     emb, boxes, outp);
}